// Round 9
// baseline (38.318 us; speedup 1.0000x reference)
//
#include <hip/hip_runtime.h>

// Shapes (fixed by the reference):
//   frames: (4, 8, 256, 256, 1) f32
//   core:   (4, 256, 256, 200)  f32  -> raw-reshaped to (4, 8, 256, 256, 1, 25)
//   out:    pred_img (4,256,256,1) ++ pred_img_i (4,8,256,256,1), f32
//
// R9: y-pair blocks. R8 (quad-coop core reads, 37.3us) staged 5 frame rows per
// 1 output row (5x redundancy, ~52MB extra traffic + ~800 instrs/block).
// Now 512-thread block = 8n x 2 y-rows x 8 groups x 4 lanes stages 6 rows for
// 2 output rows (3x redundancy, ~31MB) and amortizes per-block overhead.
//
// Carried-over rules (R3-R8, each violated once and paid for):
//  - quad-cooperative core loads: lane j of a quad loads c4[4m+j] -> one
//    contiguous 64B per quad per instruction (L2-transaction-rate fix, R8).
//  - loads issued up-front, pinned with sched_barrier(0) (else scheduler
//    sinks them into the FMA loop: VGPR 60, 135us latency-bound).
//  - NO nontemporal loads (they re-sink past the barrier: R3, R5).
//  - keep-alive asm on weights AFTER staging (pins them live w/o early drain).
//  - stores after the last barrier (no barrier drains the write ack).
//  - XCD swizzle, nwg%8==0 -> bijective.
#define H 256
#define W 256

typedef float f4 __attribute__((ext_vector_type(4)));

__global__ __launch_bounds__(512, 4)
void kpn_ypair(const float* __restrict__ frames, const float* __restrict__ core,
               float* __restrict__ pred, float* __restrict__ pred_i) {
  // frame staging [n][r][c]: 8 frames x 6 rows x 10 float4 (x = xq*32-4 .. +35)
  __shared__ f4 smem[8 * 6 * 10];   // 7680 B
  __shared__ f4 red[128];           // 2 KB, disjoint

  const int tid = threadIdx.x;
  const int bid = blockIdx.x;
  const int blk = (bid & 7) * 512 + (bid >> 3);   // XCD swizzle (4096%8==0)
  const int xq  = blk & 7;            // 32-px segment of the row
  const int yp  = (blk >> 3) & 127;   // y-pair index
  const int b   = blk >> 10;
  const int y0  = yp * 2;

  const int n  = tid >> 6;            // burst frame 0..7
  const int yl = (tid >> 5) & 1;      // row within the pair
  const int q  = (tid >> 2) & 7;      // 4-px group within the 32-px segment
  const int j  = tid & 3;             // lane-in-quad

  // ---- quad-cooperative core loads: quad reads contiguous 64B per instr ----
  const int y = y0 + yl;
  const int g = ((b * 8 + n) * 256 + y) * 64 + xq * 8 + q;   // global 4-px group
  const f4* c4 = (const f4*)(core + (size_t)g * 100);
  f4 wv[7];
#pragma unroll
  for (int m = 0; m < 6; ++m) {
    wv[m] = c4[4 * m + j];
  }
  wv[6] = c4[24];                     // only j==0 uses it (1 line per quad)
  __builtin_amdgcn_sched_barrier(0);  // do NOT sink these loads past staging

  // ---- cooperative frame staging: 8 n x 6 rows x 10 float4 ----
  if (tid < 480) {
    const int nn  = tid / 60;
    const int rem = tid - nn * 60;
    const int r   = rem / 10;
    const int c   = rem - r * 10;
    const int yy  = y0 + r - 2;
    const int x4  = xq * 32 + (c - 1) * 4;   // -4 .. 256, float4-aligned
    f4 v = {0.f, 0.f, 0.f, 0.f};
    if ((unsigned)yy < (unsigned)H && (unsigned)x4 <= 252u) {
      v = *(const f4*)(frames + ((size_t)(b * 8 + nn) * H + yy) * W + x4);
    }
    smem[(nn * 6 + r) * 10 + c] = v;
  }
  // keep weight loads live here (allocator can't sink them into the FMAs)
#pragma unroll
  for (int m = 0; m < 7; ++m) {
    asm volatile("" : "+v"(wv[m]));
  }
  __syncthreads();

  // ---- per-lane 12-float window per row (quad-uniform -> LDS broadcast) ----
  f4 w4[5][3];
#pragma unroll
  for (int ki = 0; ki < 5; ++ki) {
    const f4* row = &smem[(n * 6 + yl + ki) * 10 + q];   // floats x0-4 .. x0+7
    w4[ki][0] = row[0]; w4[ki][1] = row[1]; w4[ki][2] = row[2];
  }

  // ---- partial sums: lane j covers flat weights f = 16m+4j+e ----
  f4 acc = {0.f, 0.f, 0.f, 0.f};
#define DO_F(J, M, E)                                                     \
  { constexpr int f  = 16 * (M) + 4 * (J) + (E);                          \
    constexpr int p  = f / 25, kd = f % 25;                               \
    constexpr int ki = kd / 5, kj = kd % 5, wx = p + kj + 2;              \
    acc[p] += wv[M][E] * w4[ki][wx >> 2][wx & 3]; }
#define DO4(J, M) DO_F(J, M, 0) DO_F(J, M, 1) DO_F(J, M, 2) DO_F(J, M, 3)
  switch (j) {
    case 0: DO4(0,0) DO4(0,1) DO4(0,2) DO4(0,3) DO4(0,4) DO4(0,5) DO4(0,6) break;
    case 1: DO4(1,0) DO4(1,1) DO4(1,2) DO4(1,3) DO4(1,4) DO4(1,5) break;
    case 2: DO4(2,0) DO4(2,1) DO4(2,2) DO4(2,3) DO4(2,4) DO4(2,5) break;
    default:DO4(3,0) DO4(3,1) DO4(3,2) DO4(3,3) DO4(3,4) DO4(3,5) break;
  }
#undef DO4
#undef DO_F

  // ---- quad butterfly: every lane gets the full 4-pixel sums ----
#pragma unroll
  for (int c = 0; c < 4; ++c) {
    acc[c] += __shfl_xor(acc[c], 1, 64);
    acc[c] += __shfl_xor(acc[c], 2, 64);
  }

  // ---- block mean over n -> pred ----
  if (j == 0) red[yl * 64 + n * 8 + q] = acc;
  __syncthreads();
  if (tid < 64) {
    const int ylr = tid >> 5;           // row within pair
    const int px  = tid & 31;           // pixel within the 32-px segment
    const int qq  = px >> 2, p = px & 3;
    float s = 0.f;
#pragma unroll
    for (int k = 0; k < 8; ++k) {
      s += red[ylr * 64 + k * 8 + qq][p];
    }
    s *= 0.125f;
    __builtin_nontemporal_store(
        s, pred + ((size_t)b * 256 + y0 + ylr) * 256 + xq * 32 + px);
  }

  // ---- pred_img_i: lane j stores pixel j -> fully contiguous quad store ----
  float out = (j == 0) ? acc[0] : (j == 1) ? acc[1] : (j == 2) ? acc[2] : acc[3];
  __builtin_nontemporal_store(out, pred_i + (size_t)g * 4 + j);
}

extern "C" void kernel_launch(void* const* d_in, const int* in_sizes, int n_in,
                              void* d_out, int out_size, void* d_ws, size_t ws_size,
                              hipStream_t stream) {
  const float* frames = (const float*)d_in[0];
  const float* core   = (const float*)d_in[1];
  float* pred   = (float*)d_out;                     // (4,256,256,1)
  float* pred_i = pred + (size_t)4 * H * W;          // (4,8,256,256,1)

  hipLaunchKernelGGL(kpn_ypair, dim3(4096), dim3(512), 0, stream,
                     frames, core, pred, pred_i);
}

// Round 10
// 37.486 us; speedup vs baseline: 1.0222x; 1.0222x over previous
//
#include <hip/hip_runtime.h>

// Shapes (fixed by the reference):
//   frames: (4, 8, 256, 256, 1) f32
//   core:   (4, 256, 256, 200)  f32  -> raw-reshaped to (4, 8, 256, 256, 1, 25)
//   out:    pred_img (4,256,256,1) ++ pred_img_i (4,8,256,256,1), f32
//
// R10 = exact revert to R8 (37.3us), the best measured kernel.
// R9 (512-thread y-pair blocks, less staging redundancy) REGRESSED to 38.3us:
// frames are L3-resident so staging redundancy costs ~nothing, while the
// wider barrier scope (8 waves) hurt. Stream-side levers were the only wins:
//   R2  up-front MLP on 25 core loads          135 -> 44 us
//   R7  occupancy 12->16 waves/CU + XCD swizzle 44 -> 39 us
//   R8  quad-coop core reads (64B/quad/instr,
//       fixes L2-transaction-rate bound)        39 -> 37.3 us
// Measured: FETCH 212.7MB + WRITE 9.4MB at 6.29TB/s ceiling = 35.3us floor;
// 37.3us = 94.6% of practical roofline.
//
// Hard-won schedule rules (each violated once and paid for):
//  - loads issued up-front, pinned with sched_barrier(0) (else scheduler
//    sinks them into the FMA loop: VGPR 60, VALUBusy 3%, 135us).
//  - NO nontemporal loads (they re-sink past the barrier: R3, R5).
//  - keep-alive asm on weights AFTER staging (pins them live, no early drain).
//  - stores after the last barrier (no barrier drains the write ack).
//  - XCD swizzle, nwg%8==0 -> bijective.
#define H 256
#define W 256

typedef float f4 __attribute__((ext_vector_type(4)));

__global__ __launch_bounds__(256, 4)
void kpn_quad(const float* __restrict__ frames, const float* __restrict__ core,
              float* __restrict__ pred, float* __restrict__ pred_i) {
  // frame staging [n][r][c]: 8 frames x 5 rows x 10 float4 (x = xq*32-4 .. +35)
  __shared__ f4 smem[8 * 5 * 10];   // 6400 B
  __shared__ f4 red[64];            // 1 KB, disjoint

  const int tid = threadIdx.x;
  const int bid = blockIdx.x;
  const int blk = (bid & 7) * 1024 + (bid >> 3);   // XCD swizzle (8192%8==0)
  const int xq  = blk & 7;            // 32-px segment of the row
  const int y   = (blk >> 3) & 255;
  const int b   = blk >> 11;

  const int n = tid >> 5;             // burst frame 0..7
  const int q = (tid >> 2) & 7;       // 4-px group within the 32-px segment
  const int j = tid & 3;              // lane-in-quad

  // ---- quad-cooperative core loads: quad reads contiguous 64B per instr ----
  const int g = ((b * 8 + n) * 256 + y) * 64 + xq * 8 + q;   // global 4-px group
  const f4* c4 = (const f4*)(core + (size_t)g * 100);
  f4 wv[7];
#pragma unroll
  for (int m = 0; m < 6; ++m) {
    wv[m] = c4[4 * m + j];
  }
  wv[6] = c4[24];                     // only j==0 uses it (1 line per quad)
  __builtin_amdgcn_sched_barrier(0);  // do NOT sink these loads past staging

  // ---- cooperative frame staging: 8 n x 5 rows x 10 float4 ----
  for (int i = tid; i < 400; i += 256) {
    const int nn  = i / 50;
    const int rem = i - nn * 50;
    const int r   = rem / 10;
    const int c   = rem - r * 10;
    const int yy  = y + r - 2;
    const int x4  = xq * 32 + (c - 1) * 4;   // -4 .. 256, float4-aligned
    f4 v = {0.f, 0.f, 0.f, 0.f};
    if ((unsigned)yy < (unsigned)H && (unsigned)x4 <= 252u) {
      v = *(const f4*)(frames + ((size_t)(b * 8 + nn) * H + yy) * W + x4);
    }
    smem[i] = v;
  }
  // keep weight loads live here (allocator can't sink them into the FMAs)
#pragma unroll
  for (int m = 0; m < 7; ++m) {
    asm volatile("" : "+v"(wv[m]));
  }
  __syncthreads();

  // ---- per-lane 12-float window per row (quad-uniform -> LDS broadcast) ----
  f4 w4[5][3];
#pragma unroll
  for (int ki = 0; ki < 5; ++ki) {
    const f4* row = &smem[(n * 5 + ki) * 10 + q];   // floats x0-4 .. x0+7
    w4[ki][0] = row[0]; w4[ki][1] = row[1]; w4[ki][2] = row[2];
  }

  // ---- partial sums: lane j covers flat weights f = 16m+4j+e ----
  f4 acc = {0.f, 0.f, 0.f, 0.f};
#define DO_F(J, M, E)                                                     \
  { constexpr int f  = 16 * (M) + 4 * (J) + (E);                          \
    constexpr int p  = f / 25, kd = f % 25;                               \
    constexpr int ki = kd / 5, kj = kd % 5, wx = p + kj + 2;              \
    acc[p] += wv[M][E] * w4[ki][wx >> 2][wx & 3]; }
#define DO4(J, M) DO_F(J, M, 0) DO_F(J, M, 1) DO_F(J, M, 2) DO_F(J, M, 3)
  switch (j) {
    case 0: DO4(0,0) DO4(0,1) DO4(0,2) DO4(0,3) DO4(0,4) DO4(0,5) DO4(0,6) break;
    case 1: DO4(1,0) DO4(1,1) DO4(1,2) DO4(1,3) DO4(1,4) DO4(1,5) break;
    case 2: DO4(2,0) DO4(2,1) DO4(2,2) DO4(2,3) DO4(2,4) DO4(2,5) break;
    default:DO4(3,0) DO4(3,1) DO4(3,2) DO4(3,3) DO4(3,4) DO4(3,5) break;
  }
#undef DO4
#undef DO_F

  // ---- quad butterfly: every lane gets the full 4-pixel sums ----
#pragma unroll
  for (int c = 0; c < 4; ++c) {
    acc[c] += __shfl_xor(acc[c], 1, 64);
    acc[c] += __shfl_xor(acc[c], 2, 64);
  }

  // ---- block mean over n -> pred (single extra barrier) ----
  if (j == 0) red[tid >> 2] = acc;    // red[n*8+q]
  __syncthreads();
  if (tid < 32) {
    const int qq = tid >> 2, p = tid & 3;
    float s = 0.f;
#pragma unroll
    for (int k = 0; k < 8; ++k) {
      s += red[k * 8 + qq][p];
    }
    s *= 0.125f;
    __builtin_nontemporal_store(
        s, pred + ((size_t)b * 256 + y) * 256 + xq * 32 + tid);
  }

  // ---- pred_img_i: lane j stores pixel j -> fully contiguous quad store ----
  float out = (j == 0) ? acc[0] : (j == 1) ? acc[1] : (j == 2) ? acc[2] : acc[3];
  __builtin_nontemporal_store(out, pred_i + (size_t)g * 4 + j);
}

extern "C" void kernel_launch(void* const* d_in, const int* in_sizes, int n_in,
                              void* d_out, int out_size, void* d_ws, size_t ws_size,
                              hipStream_t stream) {
  const float* frames = (const float*)d_in[0];
  const float* core   = (const float*)d_in[1];
  float* pred   = (float*)d_out;                     // (4,256,256,1)
  float* pred_i = pred + (size_t)4 * H * W;          // (4,8,256,256,1)

  hipLaunchKernelGGL(kpn_quad, dim3(8192), dim3(256), 0, stream,
                     frames, core, pred, pred_i);
}